// Round 2
// baseline (7772.681 us; speedup 1.0000x reference)
//
#include <hip/hip_runtime.h>

#define BATCH 1024
#define TT    512
#define HH    64
#define NB    2                 // batches per block
#define NBLK  (BATCH / NB)      // 512 blocks -> 2 blocks/CU if VGPR <= 85

__device__ __forceinline__ float sigmoidf_(float x) {
    return 1.0f / (1.0f + __expf(-x));
}
__device__ __forceinline__ float tanhf_(float x) {
    return 1.0f - 2.0f / (1.0f + __expf(2.0f * x));
}
__device__ __forceinline__ float2 fma2(float w, float2 h, float2 a) {
    // hoping for v_pk_fma_f32; correct either way
    a.x = fmaf(w, h.x, a.x);
    a.y = fmaf(w, h.y, a.y);
    return a;
}

// 512 blocks x 768 threads. Block owns NB=2 batches for all T.
// Pipelined 1-step skew between layers -> one matvec phase + one pointwise
// phase per tick (2 barriers/tick, 513 ticks).
//   Group A (tid   0..255): g1(s)  = bias1 + Wx*x(s) + w_hh0 @ h1(s-1)   [s <  T]
//   Group B (tid 256..511): p_ih   = w_ih1 @ h1(s-1)                      [s >= 1]
//   Group C (tid 512..767): p_hh   = bias2 + w_hh1 @ h2(s-2)              [s >= 1]
// Pointwise: tid 0..127  -> layer1 (h1(s), c1 in regs)      [s <  T]
//            tid 256..383 -> layer2 (h2(s-1), c2 in regs)   [s >= 1]
__global__ __launch_bounds__(768, 6) void lstm_fused(
    const float* __restrict__ x,
    const float* __restrict__ w_ih0, const float* __restrict__ w_hh0,
    const float* __restrict__ b_ih0, const float* __restrict__ b_hh0,
    const float* __restrict__ w_ih1, const float* __restrict__ w_hh1,
    const float* __restrict__ b_ih1, const float* __restrict__ b_hh1,
    const float* __restrict__ w_out, const float* __restrict__ b_out,
    float* __restrict__ out)
{
    __shared__ float2 h1s[HH];        // h1[j] for 2 batches
    __shared__ float2 h2s[HH];        // h2[j] for 2 batches
    __shared__ float2 g1s[4 * HH];    // layer1 gates
    __shared__ float2 g2bs[4 * HH];   // layer2 ih partial
    __shared__ float2 g2cs[4 * HH];   // layer2 hh partial (incl. bias)
    __shared__ float  xs[TT * 3 * NB];// whole x slice: [(t*3+d)*NB + b]
    __shared__ float  lg[NB][4];

    const int tid   = threadIdx.x;
    const int group = tid >> 8;       // wave-uniform
    const int g     = tid & 255;
    const int b0    = blockIdx.x * NB;

    // ---- persistent weight row in registers (64 VGPRs) ----
    float wreg[HH];
    const float* wsrc = (group == 0) ? (w_hh0 + g * HH)
                      : (group == 1) ? (w_ih1 + g * HH)
                                     : (w_hh1 + g * HH);
    #pragma unroll
    for (int j = 0; j < HH; ++j) wreg[j] = wsrc[j];

    float wx0 = 0.f, wx1 = 0.f, wx2 = 0.f, bias = 0.f;
    if (group == 0) {
        wx0  = w_ih0[g * 3 + 0];
        wx1  = w_ih0[g * 3 + 1];
        wx2  = w_ih0[g * 3 + 2];
        bias = b_ih0[g] + b_hh0[g];
    } else if (group == 2) {
        bias = b_ih1[g] + b_hh1[g];
    }

    // ---- preload entire x slice for this block's batches (12 KB, coalesced) ----
    for (int idx = tid; idx < TT * 3 * NB; idx += 768) {
        const int b   = idx / (TT * 3);
        const int rem = idx - b * (TT * 3);            // t*3 + d
        xs[rem * NB + b] = x[(size_t)(b0 + b) * (TT * 3) + rem];
    }

    if (tid < HH) {
        h1s[tid] = make_float2(0.f, 0.f);
        h2s[tid] = make_float2(0.f, 0.f);
    }
    float c_reg = 0.0f;   // tid<128: c1[j][b]; tid in [256,384): c2[j][b]
    __syncthreads();

    for (int s = 0; s <= TT; ++s) {
        // ================= phase alpha: matvecs =================
        if (group == 0) {
            if (s < TT) {
                float2 a = make_float2(bias, bias);
                const int xb = s * 6;   // s*3*NB
                a.x += wx0 * xs[xb + 0] + wx1 * xs[xb + 2] + wx2 * xs[xb + 4];
                a.y += wx0 * xs[xb + 1] + wx1 * xs[xb + 3] + wx2 * xs[xb + 5];
                #pragma unroll
                for (int j = 0; j < HH; ++j)
                    a = fma2(wreg[j], h1s[j], a);       // broadcast ds_read_b64
                g1s[g] = a;
            }
        } else if (group == 1) {
            if (s >= 1) {
                float2 a = make_float2(0.f, 0.f);
                #pragma unroll
                for (int j = 0; j < HH; ++j)
                    a = fma2(wreg[j], h1s[j], a);
                g2bs[g] = a;
            }
        } else {
            if (s >= 1) {
                float2 a = make_float2(bias, bias);
                #pragma unroll
                for (int j = 0; j < HH; ++j)
                    a = fma2(wreg[j], h2s[j], a);
                g2cs[g] = a;
            }
        }
        __syncthreads();

        // ================= phase beta: pointwise =================
        if (tid < 128) {                       // layer 1, step s
            if (s < TT) {
                const int b = tid & 1, j = tid >> 1;
                const float* gf = (const float*)g1s;
                const float iv = gf[(j      ) * 2 + b];
                const float fv = gf[(j +  64) * 2 + b];
                const float gv = gf[(j + 128) * 2 + b];
                const float ov = gf[(j + 192) * 2 + b];
                const float is = sigmoidf_(iv);
                const float fs = sigmoidf_(fv);
                const float gt = tanhf_(gv);
                const float os = sigmoidf_(ov);
                c_reg = fs * c_reg + is * gt;
                ((float*)h1s)[j * 2 + b] = os * tanhf_(c_reg);
            }
        } else if (tid >= 256 && tid < 384) {  // layer 2, step s-1
            if (s >= 1) {
                const int q = tid - 256;
                const int b = q & 1, j = q >> 1;
                const float* gb = (const float*)g2bs;
                const float* gc = (const float*)g2cs;
                const float iv = gb[(j      ) * 2 + b] + gc[(j      ) * 2 + b];
                const float fv = gb[(j +  64) * 2 + b] + gc[(j +  64) * 2 + b];
                const float gv = gb[(j + 128) * 2 + b] + gc[(j + 128) * 2 + b];
                const float ov = gb[(j + 192) * 2 + b] + gc[(j + 192) * 2 + b];
                const float is = sigmoidf_(iv);
                const float fs = sigmoidf_(fv);
                const float gt = tanhf_(gv);
                const float os = sigmoidf_(ov);
                c_reg = fs * c_reg + is * gt;
                ((float*)h2s)[j * 2 + b] = os * tanhf_(c_reg);
            }
        }
        __syncthreads();
    }

    // ---- epilogue: logits + softmax ----
    if (tid < 8) {
        const int b = tid & 1, o = tid >> 1;
        float acc = b_out[o];
        const float* h2f = (const float*)h2s;
        #pragma unroll
        for (int j = 0; j < HH; ++j)
            acc = fmaf(w_out[o * HH + j], h2f[j * 2 + b], acc);
        lg[b][o] = acc;
    }
    __syncthreads();
    if (tid < NB) {
        const int b = tid;
        const float l0 = lg[b][0], l1 = lg[b][1], l2 = lg[b][2], l3 = lg[b][3];
        const float m  = fmaxf(fmaxf(l0, l1), fmaxf(l2, l3));
        const float e0 = __expf(l0 - m), e1 = __expf(l1 - m);
        const float e2 = __expf(l2 - m), e3 = __expf(l3 - m);
        const float sum = 1.0f / (e0 + e1 + e2 + e3);
        out[(b0 + b) * 4 + 0] = e0 * sum;
        out[(b0 + b) * 4 + 1] = e1 * sum;
        out[(b0 + b) * 4 + 2] = e2 * sum;
        out[(b0 + b) * 4 + 3] = e3 * sum;
    }
}

extern "C" void kernel_launch(void* const* d_in, const int* in_sizes, int n_in,
                              void* d_out, int out_size, void* d_ws, size_t ws_size,
                              hipStream_t stream) {
    const float* x     = (const float*)d_in[0];
    const float* w_ih0 = (const float*)d_in[1];
    const float* w_hh0 = (const float*)d_in[2];
    const float* b_ih0 = (const float*)d_in[3];
    const float* b_hh0 = (const float*)d_in[4];
    const float* w_ih1 = (const float*)d_in[5];
    const float* w_hh1 = (const float*)d_in[6];
    const float* b_ih1 = (const float*)d_in[7];
    const float* b_hh1 = (const float*)d_in[8];
    const float* w_out = (const float*)d_in[9];
    const float* b_out = (const float*)d_in[10];
    float* out = (float*)d_out;

    hipLaunchKernelGGL(lstm_fused, dim3(NBLK), dim3(768), 0, stream,
                       x, w_ih0, w_hh0, b_ih0, b_hh0,
                       w_ih1, w_hh1, b_ih1, b_hh1,
                       w_out, b_out, out);
}

// Round 3
// 1137.611 us; speedup vs baseline: 6.8325x; 6.8325x over previous
//
#include <hip/hip_runtime.h>

#define BATCH 1024
#define TT    512
#define HH    64
#define NB    4                 // batches per block
#define NBLK  (BATCH / NB)      // 256 blocks, 1 block/CU, 12 waves resident

__device__ __forceinline__ float sigmoidf_(float x) {
    return 1.0f / (1.0f + __expf(-x));
}
__device__ __forceinline__ float tanhf_(float x) {
    return 1.0f - 2.0f / (1.0f + __expf(2.0f * x));
}

// 256 blocks x 768 threads. Block owns NB=4 batches for all T.
// Pipelined 1-step skew between layers -> one matvec phase + one pointwise
// phase per tick (2 barriers/tick, T+1 ticks).
//   Group A (tid   0..255): g1(s)  = bias1 + Wx*x(s) + w_hh0 @ h1(s-1)   [s <  T]
//   Group B (tid 256..511): p_ih   = w_ih1 @ h1(s-1)                      [s >= 1]
//   Group C (tid 512..767): p_hh   = bias2 + w_hh1 @ h2(s-2)              [s >= 1]
// Pointwise beta: group A -> h1(s), c1 in regs; group B -> h2(s-1), c2 in regs.
// NOTE: no min-waves clamp — wreg[64] + hb[8] needs ~120 VGPRs; at 12 waves/CU
// (3/SIMD) anything <= 170 VGPRs costs nothing (round-2 lesson: forcing 6/SIMD
// spills wreg to scratch -> 27 GB of HBM traffic).
__global__ __launch_bounds__(768) void lstm_fused(
    const float* __restrict__ x,
    const float* __restrict__ w_ih0, const float* __restrict__ w_hh0,
    const float* __restrict__ b_ih0, const float* __restrict__ b_hh0,
    const float* __restrict__ w_ih1, const float* __restrict__ w_hh1,
    const float* __restrict__ b_ih1, const float* __restrict__ b_hh1,
    const float* __restrict__ w_out, const float* __restrict__ b_out,
    float* __restrict__ out)
{
    __shared__ float4 h1s[HH];         // h1[j] for 4 batches
    __shared__ float4 h2s[HH];         // h2[j] for 4 batches
    __shared__ float4 g1s[4 * HH];     // layer1 gates
    __shared__ float4 g2bs[4 * HH];    // layer2 ih partial
    __shared__ float4 g2cs[4 * HH];    // layer2 hh partial (incl. bias)
    __shared__ float4 xs[TT * 3];      // whole x slice: [t*3+d] -> 4 batches
    __shared__ float  lg[NB][4];

    const int tid   = threadIdx.x;
    const int group = tid >> 8;        // wave-uniform
    const int g     = tid & 255;
    const int b0    = blockIdx.x * NB;

    // ---- persistent weight row in registers (64 VGPRs) ----
    float wreg[HH];
    const float* wsrc = (group == 0) ? (w_hh0 + g * HH)
                      : (group == 1) ? (w_ih1 + g * HH)
                                     : (w_hh1 + g * HH);
    #pragma unroll
    for (int j = 0; j < HH; ++j) wreg[j] = wsrc[j];

    float wx0 = 0.f, wx1 = 0.f, wx2 = 0.f, bias = 0.f;
    if (group == 0) {
        wx0  = w_ih0[g * 3 + 0];
        wx1  = w_ih0[g * 3 + 1];
        wx2  = w_ih0[g * 3 + 2];
        bias = b_ih0[g] + b_hh0[g];
    } else if (group == 2) {
        bias = b_ih1[g] + b_hh1[g];
    }

    // ---- preload entire x slice (24 KB) into LDS, [t*3+d][b] layout ----
    {
        float* xsf = (float*)xs;
        for (int idx = tid; idx < TT * 3 * NB; idx += 768) {
            const int b   = idx / (TT * 3);
            const int rem = idx - b * (TT * 3);       // t*3 + d
            xsf[rem * NB + b] = x[(size_t)(b0 + b) * (TT * 3) + rem];
        }
    }

    if (tid < HH) {
        h1s[tid] = make_float4(0.f, 0.f, 0.f, 0.f);
        h2s[tid] = make_float4(0.f, 0.f, 0.f, 0.f);
    }
    float c_reg = 0.0f;   // group A: c1[j][b]; group B: c2[j][b]
    __syncthreads();

    for (int s = 0; s <= TT; ++s) {
        // ================= phase alpha: three concurrent matvecs =================
        if (group == 0) {
            if (s < TT) {
                float a0 = bias, a1 = bias, a2 = bias, a3 = bias;
                const float4 xv0 = xs[s * 3 + 0];
                const float4 xv1 = xs[s * 3 + 1];
                const float4 xv2 = xs[s * 3 + 2];
                a0 += wx0 * xv0.x + wx1 * xv1.x + wx2 * xv2.x;
                a1 += wx0 * xv0.y + wx1 * xv1.y + wx2 * xv2.y;
                a2 += wx0 * xv0.z + wx1 * xv1.z + wx2 * xv2.z;
                a3 += wx0 * xv0.w + wx1 * xv1.w + wx2 * xv2.w;
                // 8-deep rolling prefetch of broadcast ds_read_b128
                float4 hb[8];
                #pragma unroll
                for (int j = 0; j < 8; ++j) hb[j] = h1s[j];
                #pragma unroll
                for (int j = 0; j < HH; ++j) {
                    const float4 hv = hb[j & 7];
                    if (j + 8 < HH) hb[j & 7] = h1s[j + 8];
                    a0 = fmaf(wreg[j], hv.x, a0);
                    a1 = fmaf(wreg[j], hv.y, a1);
                    a2 = fmaf(wreg[j], hv.z, a2);
                    a3 = fmaf(wreg[j], hv.w, a3);
                }
                g1s[g] = make_float4(a0, a1, a2, a3);
            }
        } else if (group == 1) {
            if (s >= 1) {
                float a0 = 0.f, a1 = 0.f, a2 = 0.f, a3 = 0.f;
                float4 hb[8];
                #pragma unroll
                for (int j = 0; j < 8; ++j) hb[j] = h1s[j];
                #pragma unroll
                for (int j = 0; j < HH; ++j) {
                    const float4 hv = hb[j & 7];
                    if (j + 8 < HH) hb[j & 7] = h1s[j + 8];
                    a0 = fmaf(wreg[j], hv.x, a0);
                    a1 = fmaf(wreg[j], hv.y, a1);
                    a2 = fmaf(wreg[j], hv.z, a2);
                    a3 = fmaf(wreg[j], hv.w, a3);
                }
                g2bs[g] = make_float4(a0, a1, a2, a3);
            }
        } else {
            if (s >= 1) {
                float a0 = bias, a1 = bias, a2 = bias, a3 = bias;
                float4 hb[8];
                #pragma unroll
                for (int j = 0; j < 8; ++j) hb[j] = h2s[j];
                #pragma unroll
                for (int j = 0; j < HH; ++j) {
                    const float4 hv = hb[j & 7];
                    if (j + 8 < HH) hb[j & 7] = h2s[j + 8];
                    a0 = fmaf(wreg[j], hv.x, a0);
                    a1 = fmaf(wreg[j], hv.y, a1);
                    a2 = fmaf(wreg[j], hv.z, a2);
                    a3 = fmaf(wreg[j], hv.w, a3);
                }
                g2cs[g] = make_float4(a0, a1, a2, a3);
            }
        }
        __syncthreads();

        // ================= phase beta: pointwise =================
        if (group == 0) {                      // layer 1, step s
            if (s < TT) {
                const int b = g & 3, j = g >> 2;
                const float* gf = (const float*)g1s;
                const float iv = gf[(j      ) * 4 + b];
                const float fv = gf[(j +  64) * 4 + b];
                const float gv = gf[(j + 128) * 4 + b];
                const float ov = gf[(j + 192) * 4 + b];
                const float is = sigmoidf_(iv);
                const float fs = sigmoidf_(fv);
                const float gt = tanhf_(gv);
                const float os = sigmoidf_(ov);
                c_reg = fs * c_reg + is * gt;
                ((float*)h1s)[j * 4 + b] = os * tanhf_(c_reg);
            }
        } else if (group == 1) {               // layer 2, step s-1
            if (s >= 1) {
                const int b = g & 3, j = g >> 2;
                const float* gb = (const float*)g2bs;
                const float* gc = (const float*)g2cs;
                const float iv = gb[(j      ) * 4 + b] + gc[(j      ) * 4 + b];
                const float fv = gb[(j +  64) * 4 + b] + gc[(j +  64) * 4 + b];
                const float gv = gb[(j + 128) * 4 + b] + gc[(j + 128) * 4 + b];
                const float ov = gb[(j + 192) * 4 + b] + gc[(j + 192) * 4 + b];
                const float is = sigmoidf_(iv);
                const float fs = sigmoidf_(fv);
                const float gt = tanhf_(gv);
                const float os = sigmoidf_(ov);
                c_reg = fs * c_reg + is * gt;
                ((float*)h2s)[j * 4 + b] = os * tanhf_(c_reg);
            }
        }
        __syncthreads();
    }

    // ---- epilogue: logits + softmax for the block's 4 batches ----
    if (tid < 16) {
        const int b = tid & 3, o = tid >> 2;
        float acc = b_out[o];
        const float* h2f = (const float*)h2s;
        #pragma unroll
        for (int j = 0; j < HH; ++j)
            acc = fmaf(w_out[o * HH + j], h2f[j * 4 + b], acc);
        lg[b][o] = acc;
    }
    __syncthreads();
    if (tid < NB) {
        const int b = tid;
        const float l0 = lg[b][0], l1 = lg[b][1], l2 = lg[b][2], l3 = lg[b][3];
        const float m  = fmaxf(fmaxf(l0, l1), fmaxf(l2, l3));
        const float e0 = __expf(l0 - m), e1 = __expf(l1 - m);
        const float e2 = __expf(l2 - m), e3 = __expf(l3 - m);
        const float sum = 1.0f / (e0 + e1 + e2 + e3);
        out[(b0 + b) * 4 + 0] = e0 * sum;
        out[(b0 + b) * 4 + 1] = e1 * sum;
        out[(b0 + b) * 4 + 2] = e2 * sum;
        out[(b0 + b) * 4 + 3] = e3 * sum;
    }
}

extern "C" void kernel_launch(void* const* d_in, const int* in_sizes, int n_in,
                              void* d_out, int out_size, void* d_ws, size_t ws_size,
                              hipStream_t stream) {
    const float* x     = (const float*)d_in[0];
    const float* w_ih0 = (const float*)d_in[1];
    const float* w_hh0 = (const float*)d_in[2];
    const float* b_ih0 = (const float*)d_in[3];
    const float* b_hh0 = (const float*)d_in[4];
    const float* w_ih1 = (const float*)d_in[5];
    const float* w_hh1 = (const float*)d_in[6];
    const float* b_ih1 = (const float*)d_in[7];
    const float* b_hh1 = (const float*)d_in[8];
    const float* w_out = (const float*)d_in[9];
    const float* b_out = (const float*)d_in[10];
    float* out = (float*)d_out;

    hipLaunchKernelGGL(lstm_fused, dim3(NBLK), dim3(768), 0, stream,
                       x, w_ih0, w_hh0, b_ih0, b_hh0,
                       w_ih1, w_hh1, b_ih1, b_hh1,
                       w_out, b_out, out);
}

// Round 4
// 861.013 us; speedup vs baseline: 9.0274x; 1.3212x over previous
//
#include <hip/hip_runtime.h>

#define BATCH 1024
#define TT    512
#define HH    64
#define NB    4
#define NBLK  (BATCH / NB)   // 256 blocks, 1 block/CU

__device__ __forceinline__ float sigmoidf_(float x) {
    return 1.0f / (1.0f + __expf(-x));
}
__device__ __forceinline__ float tanhf_(float x) {
    return 1.0f - 2.0f / (1.0f + __expf(2.0f * x));
}
// quad_perm lane swaps (pure VALU; no LDS pipe)
__device__ __forceinline__ float dpp_xor1(float v) {
    return __int_as_float(__builtin_amdgcn_mov_dpp(__float_as_int(v), 0xB1, 0xF, 0xF, true));
}
__device__ __forceinline__ float dpp_xor2(float v) {
    return __int_as_float(__builtin_amdgcn_mov_dpp(__float_as_int(v), 0x4E, 0xF, 0xF, true));
}
__device__ __forceinline__ float sel4(float a0, float a1, float a2, float a3, int s) {
    float r = a0;
    r = (s == 1) ? a1 : r;
    r = (s == 2) ? a2 : r;
    r = (s == 3) ? a3 : r;
    return r;
}

// 256 blocks x 768 threads; block owns 4 batches for all T.
// Lane (u = q>>2, s = q&3) owns gate rows {u, u+64, u+128, u+192} with
// K-slice j = 4*jj + s (jj=0..15). Quad (same u) reduces via DPP.
// Skew (1 barrier/tick, ticks 0..T+1):
//   A (tid 0..255):   g1(t) from h1(t-1)+x(t) -> pointwise -> h1(t)
//   B (tid 256..511): p_ih = w_ih1 @ h1(t-1)  -> LDS
//   C (tid 512..767): w_hh1 @ h2(t-3) + p_ih(t-1) -> pointwise -> h2(t-2)
__global__ __launch_bounds__(768) void lstm_fused(
    const float* __restrict__ x,
    const float* __restrict__ w_ih0, const float* __restrict__ w_hh0,
    const float* __restrict__ b_ih0, const float* __restrict__ b_hh0,
    const float* __restrict__ w_ih1, const float* __restrict__ w_hh1,
    const float* __restrict__ b_ih1, const float* __restrict__ b_hh1,
    const float* __restrict__ w_out, const float* __restrict__ b_out,
    float* __restrict__ out)
{
    __shared__ float4 h1s[2][HH];        // ping-pong h1, [u] -> 4 batches
    __shared__ float4 h2s[2][HH];        // ping-pong h2
    __shared__ float4 pis[2][HH][NB];    // ping-pong p_ih, [u][b] -> 4 gates
    __shared__ float4 xs[TT * 3];        // x slice, [t*3+d] -> 4 batches
    __shared__ float  lg[NB][4];

    const int tid   = threadIdx.x;
    const int group = tid >> 8;          // wave-uniform
    const int q     = tid & 255;
    const int u     = q >> 2;            // hidden unit
    const int s     = q & 3;             // K-slice / batch lane
    const int b0    = blockIdx.x * NB;

    // ---- per-lane weights: wreg[gate][jj] = W[gate*64+u][4*jj+s] ----
    float wreg[4][16];
    const float* Wm = (group == 0) ? w_hh0 : (group == 1) ? w_ih1 : w_hh1;
    #pragma unroll
    for (int g_ = 0; g_ < 4; ++g_) {
        const float* row = Wm + (g_ * 64 + u) * HH;
        #pragma unroll
        for (int jj = 0; jj < 16; ++jj) wreg[g_][jj] = row[4 * jj + s];
    }

    float wx[4]   = {0.f, 0.f, 0.f, 0.f};  // A: w_ih0[row][d=s] (s<3), else 0
    float bias[4] = {0.f, 0.f, 0.f, 0.f};  // slice-3 lane carries the bias
    if (group == 0) {
        #pragma unroll
        for (int g_ = 0; g_ < 4; ++g_) {
            const int row = g_ * 64 + u;
            if (s < 3)  wx[g_]   = w_ih0[row * 3 + s];
            if (s == 3) bias[g_] = b_ih0[row] + b_hh0[row];
        }
    } else if (group == 2) {
        #pragma unroll
        for (int g_ = 0; g_ < 4; ++g_) {
            const int row = g_ * 64 + u;
            if (s == 3) bias[g_] = b_ih1[row] + b_hh1[row];
        }
    }
    const int xoff = (s < 3) ? s : 0;    // s==3 reads d=0 but wx==0

    // ---- preload x slice (24 KB), layout [t*3+d][b] ----
    {
        float* xsf = (float*)xs;
        for (int idx = tid; idx < TT * 3 * NB; idx += 768) {
            const int b   = idx / (TT * 3);
            const int rem = idx - b * (TT * 3);
            xsf[rem * NB + b] = x[(size_t)(b0 + b) * (TT * 3) + rem];
        }
    }
    if (tid < 2 * HH) {
        ((float4*)h1s)[tid] = make_float4(0.f, 0.f, 0.f, 0.f);
        ((float4*)h2s)[tid] = make_float4(0.f, 0.f, 0.f, 0.f);
    }
    float c_reg = 0.0f;                  // A: c1[batch s]; C: c2[batch s]
    __syncthreads();

    for (int t = 0; t <= TT + 1; ++t) {
        if (group == 0) {
            if (t < TT) {
                float acc[4][4];
                const float4 xv = xs[t * 3 + xoff];
                #pragma unroll
                for (int g_ = 0; g_ < 4; ++g_) {   // init = bias + x-part (fma)
                    acc[g_][0] = fmaf(wx[g_], xv.x, bias[g_]);
                    acc[g_][1] = fmaf(wx[g_], xv.y, bias[g_]);
                    acc[g_][2] = fmaf(wx[g_], xv.z, bias[g_]);
                    acc[g_][3] = fmaf(wx[g_], xv.w, bias[g_]);
                }
                const float4* hrd = h1s[(t + 1) & 1] + s;   // + s => byte offset 16*s
                #pragma unroll
                for (int jj = 0; jj < 16; ++jj) {
                    const float4 hv = hrd[4 * jj];          // offset 64*jj bytes... (4*jj float4s)
                    #pragma unroll
                    for (int g_ = 0; g_ < 4; ++g_) {
                        acc[g_][0] = fmaf(wreg[g_][jj], hv.x, acc[g_][0]);
                        acc[g_][1] = fmaf(wreg[g_][jj], hv.y, acc[g_][1]);
                        acc[g_][2] = fmaf(wreg[g_][jj], hv.z, acc[g_][2]);
                        acc[g_][3] = fmaf(wreg[g_][jj], hv.w, acc[g_][3]);
                    }
                }
                #pragma unroll
                for (int g_ = 0; g_ < 4; ++g_)
                    #pragma unroll
                    for (int b = 0; b < 4; ++b) {
                        acc[g_][b] += dpp_xor1(acc[g_][b]);
                        acc[g_][b] += dpp_xor2(acc[g_][b]);
                    }
                const float gi = sel4(acc[0][0], acc[0][1], acc[0][2], acc[0][3], s);
                const float gf = sel4(acc[1][0], acc[1][1], acc[1][2], acc[1][3], s);
                const float gg = sel4(acc[2][0], acc[2][1], acc[2][2], acc[2][3], s);
                const float go = sel4(acc[3][0], acc[3][1], acc[3][2], acc[3][3], s);
                const float is = sigmoidf_(gi);
                const float fs = sigmoidf_(gf);
                const float gt = tanhf_(gg);
                const float os = sigmoidf_(go);
                c_reg = fs * c_reg + is * gt;
                ((float*)h1s[t & 1])[q] = os * tanhf_(c_reg);
            }
        } else if (group == 1) {
            if (t >= 1 && t <= TT) {
                float acc[4][4];
                const float4* hrd = h1s[(t + 1) & 1] + s;
                {   // jj = 0 initializes (no bias for the ih partial)
                    const float4 hv = hrd[0];
                    #pragma unroll
                    for (int g_ = 0; g_ < 4; ++g_) {
                        acc[g_][0] = wreg[g_][0] * hv.x;
                        acc[g_][1] = wreg[g_][0] * hv.y;
                        acc[g_][2] = wreg[g_][0] * hv.z;
                        acc[g_][3] = wreg[g_][0] * hv.w;
                    }
                }
                #pragma unroll
                for (int jj = 1; jj < 16; ++jj) {
                    const float4 hv = hrd[4 * jj];
                    #pragma unroll
                    for (int g_ = 0; g_ < 4; ++g_) {
                        acc[g_][0] = fmaf(wreg[g_][jj], hv.x, acc[g_][0]);
                        acc[g_][1] = fmaf(wreg[g_][jj], hv.y, acc[g_][1]);
                        acc[g_][2] = fmaf(wreg[g_][jj], hv.z, acc[g_][2]);
                        acc[g_][3] = fmaf(wreg[g_][jj], hv.w, acc[g_][3]);
                    }
                }
                #pragma unroll
                for (int g_ = 0; g_ < 4; ++g_)
                    #pragma unroll
                    for (int b = 0; b < 4; ++b) {
                        acc[g_][b] += dpp_xor1(acc[g_][b]);
                        acc[g_][b] += dpp_xor2(acc[g_][b]);
                    }
                float4 p;
                p.x = sel4(acc[0][0], acc[0][1], acc[0][2], acc[0][3], s);
                p.y = sel4(acc[1][0], acc[1][1], acc[1][2], acc[1][3], s);
                p.z = sel4(acc[2][0], acc[2][1], acc[2][2], acc[2][3], s);
                p.w = sel4(acc[3][0], acc[3][1], acc[3][2], acc[3][3], s);
                pis[t & 1][u][s] = p;
            }
        } else {
            if (t >= 2) {
                float acc[4][4];
                const float4* hrd = h2s[(t + 1) & 1] + s;
                {   // jj = 0 initializes with bias
                    const float4 hv = hrd[0];
                    #pragma unroll
                    for (int g_ = 0; g_ < 4; ++g_) {
                        acc[g_][0] = fmaf(wreg[g_][0], hv.x, bias[g_]);
                        acc[g_][1] = fmaf(wreg[g_][0], hv.y, bias[g_]);
                        acc[g_][2] = fmaf(wreg[g_][0], hv.z, bias[g_]);
                        acc[g_][3] = fmaf(wreg[g_][0], hv.w, bias[g_]);
                    }
                }
                #pragma unroll
                for (int jj = 1; jj < 16; ++jj) {
                    const float4 hv = hrd[4 * jj];
                    #pragma unroll
                    for (int g_ = 0; g_ < 4; ++g_) {
                        acc[g_][0] = fmaf(wreg[g_][jj], hv.x, acc[g_][0]);
                        acc[g_][1] = fmaf(wreg[g_][jj], hv.y, acc[g_][1]);
                        acc[g_][2] = fmaf(wreg[g_][jj], hv.z, acc[g_][2]);
                        acc[g_][3] = fmaf(wreg[g_][jj], hv.w, acc[g_][3]);
                    }
                }
                #pragma unroll
                for (int g_ = 0; g_ < 4; ++g_)
                    #pragma unroll
                    for (int b = 0; b < 4; ++b) {
                        acc[g_][b] += dpp_xor1(acc[g_][b]);
                        acc[g_][b] += dpp_xor2(acc[g_][b]);
                    }
                const float4 pv = pis[(t + 1) & 1][u][s];   // p_ih from tick t-1
                const float gi = sel4(acc[0][0], acc[0][1], acc[0][2], acc[0][3], s) + pv.x;
                const float gf = sel4(acc[1][0], acc[1][1], acc[1][2], acc[1][3], s) + pv.y;
                const float gg = sel4(acc[2][0], acc[2][1], acc[2][2], acc[2][3], s) + pv.z;
                const float go = sel4(acc[3][0], acc[3][1], acc[3][2], acc[3][3], s) + pv.w;
                const float is = sigmoidf_(gi);
                const float fs = sigmoidf_(gf);
                const float gt = tanhf_(gg);
                const float os = sigmoidf_(go);
                c_reg = fs * c_reg + is * gt;
                ((float*)h2s[t & 1])[q] = os * tanhf_(c_reg);   // h2(t-2)
            }
        }
        __syncthreads();
    }

    // ---- epilogue: logits + softmax; final h2 = h2(T-1) in buf (T+1)&1 ----
    const float* h2f = (const float*)h2s[(TT + 1) & 1];
    if (tid < 16) {
        const int b = tid & 3, o = tid >> 2;
        float acc = b_out[o];
        #pragma unroll
        for (int j = 0; j < HH; ++j)
            acc = fmaf(w_out[o * HH + j], h2f[j * 4 + b], acc);
        lg[b][o] = acc;
    }
    __syncthreads();
    if (tid < NB) {
        const int b = tid;
        const float l0 = lg[b][0], l1 = lg[b][1], l2 = lg[b][2], l3 = lg[b][3];
        const float m  = fmaxf(fmaxf(l0, l1), fmaxf(l2, l3));
        const float e0 = __expf(l0 - m), e1 = __expf(l1 - m);
        const float e2 = __expf(l2 - m), e3 = __expf(l3 - m);
        const float sum = 1.0f / (e0 + e1 + e2 + e3);
        out[(b0 + b) * 4 + 0] = e0 * sum;
        out[(b0 + b) * 4 + 1] = e1 * sum;
        out[(b0 + b) * 4 + 2] = e2 * sum;
        out[(b0 + b) * 4 + 3] = e3 * sum;
    }
}

extern "C" void kernel_launch(void* const* d_in, const int* in_sizes, int n_in,
                              void* d_out, int out_size, void* d_ws, size_t ws_size,
                              hipStream_t stream) {
    const float* x     = (const float*)d_in[0];
    const float* w_ih0 = (const float*)d_in[1];
    const float* w_hh0 = (const float*)d_in[2];
    const float* b_ih0 = (const float*)d_in[3];
    const float* b_hh0 = (const float*)d_in[4];
    const float* w_ih1 = (const float*)d_in[5];
    const float* w_hh1 = (const float*)d_in[6];
    const float* b_ih1 = (const float*)d_in[7];
    const float* b_hh1 = (const float*)d_in[8];
    const float* w_out = (const float*)d_in[9];
    const float* b_out = (const float*)d_in[10];
    float* out = (float*)d_out;

    hipLaunchKernelGGL(lstm_fused, dim3(NBLK), dim3(768), 0, stream,
                       x, w_ih0, w_hh0, b_ih0, b_hh0,
                       w_ih1, w_hh1, b_ih1, b_hh1,
                       w_out, b_out, out);
}